// Round 1
// baseline (114.941 us; speedup 1.0000x reference)
//
#include <hip/hip_runtime.h>

#define BB 2
#define NN 64
#define GG 8
#define CC 17
#define HWW 4096

// ---------------- kernel 0: valid flags per (b,g,c) ----------------
// gh >= 0 always, so valid = (sum != 0) == (max > 0).
__global__ __launch_bounds__(256) void k_valid(const float* __restrict__ gh,
                                               float* __restrict__ validws) {
    int bid = blockIdx.x;            // bid == (b*GG + g)*CC + c
    int b = bid / (GG * CC);
    int g = (bid / CC) % GG;
    int c = bid % CC;
    const float* base = gh + (size_t)bid * HWW;
    int tid = threadIdx.x;
    float m = 0.f;
    for (int i = tid; i < HWW; i += 256) m = fmaxf(m, base[i]);
    #pragma unroll
    for (int off = 32; off; off >>= 1) m = fmaxf(m, __shfl_down(m, off, 64));
    __shared__ float red[4];
    int lane = tid & 63, wid = tid >> 6;
    if (lane == 0) red[wid] = m;
    __syncthreads();
    if (tid == 0) {
        float mm = fmaxf(fmaxf(red[0], red[1]), fmaxf(red[2], red[3]));
        validws[((b * CC + c) << 3) + g] = (mm > 0.f) ? 1.f : 0.f;
    }
}

// ---------------- kernel 1: heatmap focal-cost partial sums ----------------
// One block per (b,n,c). Factored form:
//   t != 1: term = A*u - Bv*(t*u),  A = softplus(x)*p^2, Bv = x*p^2, u = (1-t)^4
//   t == 1: term = (softplus(x)-x)*(1-p)^2   (factored form is exactly 0 there)
// valid-mask and /num_kp deferred to k_final.
__global__ __launch_bounds__(256) void k_hms(const float* __restrict__ ph,
                                             const float* __restrict__ gh,
                                             float* __restrict__ S1) {
    int bid = blockIdx.x;            // (b*NN + n)*CC + c
    int c = bid % CC;
    int bn = bid / CC;               // b*NN + n
    int b = bn >> 6;
    int tid = threadIdx.x;
    const float* phb = ph + (size_t)bid * HWW;
    const float* gh0 = gh + ((size_t)(b * GG) * CC + c) * HWW;  // g-stride = CC*HWW

    float acc[GG];
    #pragma unroll
    for (int g = 0; g < GG; ++g) acc[g] = 0.f;

    for (int i = tid; i < HWW; i += 256) {
        float x = phb[i];
        float ax = fabsf(x);
        float ex = __expf(-ax);
        float l1p = __logf(1.f + ex);
        float sp = fmaxf(x, 0.f) + l1p;          // softplus(x)
        float r = 1.f / (1.f + ex);
        float p = (x >= 0.f) ? r : (1.f - r);    // sigmoid(x)
        float p2 = p * p;
        float A  = sp * p2;
        float Bv = x * p2;
        float omp = 1.f - p;
        float post = (sp - x) * omp * omp;       // positive (t==1) focal term
        #pragma unroll
        for (int g = 0; g < GG; ++g) {
            float t = gh0[(size_t)g * (CC * HWW) + i];
            float om = 1.f - t;
            float om2 = om * om;
            float u = om2 * om2;                 // (1-t)^4
            float contrib = fmaf(A, u, -(Bv * (t * u)));
            acc[g] += (t == 1.f) ? post : contrib;
        }
    }

    // block-reduce 8 sums: wave shuffle then cross-wave via LDS
    __shared__ float red[4][GG];
    int lane = tid & 63, wid = tid >> 6;
    #pragma unroll
    for (int g = 0; g < GG; ++g) {
        float v = acc[g];
        #pragma unroll
        for (int off = 32; off; off >>= 1) v += __shfl_down(v, off, 64);
        if (lane == 0) red[wid][g] = v;
    }
    __syncthreads();
    if (tid < GG) {
        float s = red[0][tid] + red[1][tid] + red[2][tid] + red[3][tid];
        S1[((size_t)bid << 3) + tid] = s;        // layout [(b*NN+n)*CC + c][g]
    }
}

// ---------------- kernel 2: combine + score + offset costs ----------------
__global__ __launch_bounds__(256) void k_final(const float* __restrict__ S1,
                                               const float* __restrict__ validws,
                                               const float* __restrict__ ps,
                                               const float* __restrict__ po,
                                               const float* __restrict__ go,
                                               float* __restrict__ out) {
    int idx = blockIdx.x * blockDim.x + threadIdx.x;
    if (idx >= BB * NN * GG) return;
    int g = idx & 7;
    int bn = idx >> 3;               // b*NN + n
    int b = bn >> 6;

    float nk = 0.f, hsum = 0.f, osum = 0.f;
    #pragma unroll
    for (int c = 0; c < CC; ++c) {
        float v = validws[((b * CC + c) << 3) + g];
        nk += v;
        hsum += v * S1[(((size_t)bn * CC + c) << 3) + g];
        int poi = (bn * CC + c) * 2;
        int goi = ((b * GG + g) * CC + c) * 2;
        float s0 = 1.f / (1.f + __expf(-po[poi]));
        float s1 = 1.f / (1.f + __expf(-po[poi + 1]));
        float d0 = s0 - go[goi];
        float d1 = s1 - go[goi + 1];
        osum += v * fmaf(d0, d0, d1 * d1);
    }
    float nkp = fmaxf(nk, 1.f);

    // score cost: ALPHA * softplus(-s) * (1-sigmoid(s))^2
    float s = ps[bn];
    float ax = fabsf(s);
    float ex = __expf(-ax);
    float spn = fmaxf(-s, 0.f) + __logf(1.f + ex);   // softplus(-s)
    float r = 1.f / (1.f + ex);
    float sg = (s >= 0.f) ? r : (1.f - r);
    float om = 1.f - sg;
    float score = 0.25f * spn * om * om;

    // HMS_W=2, SCORE_W=1, OFF_W=1, off divided by num_kp and by 2
    out[idx] = 2.f * (hsum / nkp) + score + 0.5f * (osum / nkp);
}

extern "C" void kernel_launch(void* const* d_in, const int* in_sizes, int n_in,
                              void* d_out, int out_size, void* d_ws, size_t ws_size,
                              hipStream_t stream) {
    const float* ph = (const float*)d_in[0];   // pred_hms    (B,N,C,H,W)
    const float* gh = (const float*)d_in[1];   // gt_heatmaps (B,NGT,C,H,W)
    const float* ps = (const float*)d_in[2];   // pred_scores (B,N,1)
    const float* po = (const float*)d_in[3];   // pred_offsets(B,N,C,2)
    const float* go = (const float*)d_in[4];   // gt_offsets  (B,NGT,C,2)
    float* out = (float*)d_out;                // (B,N,NGT) fp32

    float* S1 = (float*)d_ws;                          // B*N*C*G = 17408 floats
    float* validws = S1 + (size_t)BB * NN * CC * GG;   // B*C*G   = 272 floats

    k_valid<<<BB * GG * CC, 256, 0, stream>>>(gh, validws);
    k_hms<<<BB * NN * CC, 256, 0, stream>>>(ph, gh, S1);
    k_final<<<(BB * NN * GG + 255) / 256, 256, 0, stream>>>(S1, validws, ps, po, go, out);
}

// Round 2
// 114.599 us; speedup vs baseline: 1.0030x; 1.0030x over previous
//
#include <hip/hip_runtime.h>

#define BB 2
#define NN 64
#define GG 8
#define CC 17
#define HWW 4096

#define TN 4                 // preds per block (register-tiled)
#define NTILES (NN / TN)     // 16
#define HCH 2                // hw chunks
#define CHUNK (HWW / HCH)    // 2048

// ---------------- kernel 0: valid flags per (b,g,c) ----------------
// gh >= 0 always, so valid = (sum != 0) == (max > 0).
__global__ __launch_bounds__(256) void k_valid(const float* __restrict__ gh,
                                               float* __restrict__ validws) {
    int bid = blockIdx.x;            // bid == (b*GG + g)*CC + c
    int b = bid / (GG * CC);
    int g = (bid / CC) % GG;
    int c = bid % CC;
    const float* base = gh + (size_t)bid * HWW;
    int tid = threadIdx.x;
    float m = 0.f;
    for (int i = tid; i < HWW; i += 256) m = fmaxf(m, base[i]);
    #pragma unroll
    for (int off = 32; off; off >>= 1) m = fmaxf(m, __shfl_down(m, off, 64));
    __shared__ float red[4];
    int lane = tid & 63, wid = tid >> 6;
    if (lane == 0) red[wid] = m;
    __syncthreads();
    if (tid == 0) {
        float mm = fmaxf(fmaxf(red[0], red[1]), fmaxf(red[2], red[3]));
        validws[((b * CC + c) << 3) + g] = (mm > 0.f) ? 1.f : 0.f;
    }
}

// ---------------- kernel 1: heatmap focal-cost partial sums ----------------
// Block = (b, c, nt, hc). gt-side (u = (1-t)^4, tu = t*u, e = [t==1]) computed
// ONCE per element, reused across TN preds in registers.
//   t != 1: term = A*u - Bv*tu   with A = softplus(x)*p^2, Bv = x*p^2
//   t == 1: u=tu=0, term = post*e with post = (softplus(x)-x)*(1-p)^2
// valid-mask and /num_kp deferred to k_final.
__global__ __launch_bounds__(256) void k_hms(const float* __restrict__ ph,
                                             const float* __restrict__ gh,
                                             float* __restrict__ S2) {
    int bid = blockIdx.x;                 // ((b*CC + c)*NTILES + nt)*HCH + hc
    int hc = bid & (HCH - 1);
    int nt = (bid / HCH) % NTILES;
    int bc = bid / (HCH * NTILES);        // b*CC + c
    int b = bc / CC;
    int c = bc % CC;
    int tid = threadIdx.x;

    const int strideC = CC * HWW;         // stride between g's (in gh) / n's (in ph)
    const float* gh0 = gh + ((size_t)b * GG * CC + c) * HWW + hc * CHUNK;
    const float* ph0 = ph + ((size_t)b * NN * CC + (size_t)nt * TN * CC + c) * HWW + hc * CHUNK;

    float acc[TN][GG];
    #pragma unroll
    for (int j = 0; j < TN; ++j)
        #pragma unroll
        for (int g = 0; g < GG; ++g) acc[j][g] = 0.f;

    for (int i = tid; i < CHUNK; i += 256) {
        // ---- gt side, once per element ----
        float u[GG], tu[GG], e[GG];
        #pragma unroll
        for (int g = 0; g < GG; ++g) {
            float t = gh0[(size_t)g * strideC + i];
            float om = 1.f - t;
            float om2 = om * om;
            float uu = om2 * om2;           // (1-t)^4
            u[g] = uu;
            tu[g] = t * uu;
            e[g] = (t == 1.f) ? 1.f : 0.f;
        }
        // ---- pred side, TN preds ----
        float xs[TN];
        #pragma unroll
        for (int j = 0; j < TN; ++j) xs[j] = ph0[(size_t)j * strideC + i];
        #pragma unroll
        for (int j = 0; j < TN; ++j) {
            float x = xs[j];
            float ax = fabsf(x);
            float ex = __expf(-ax);
            float l1p = __logf(1.f + ex);
            float sp = fmaxf(x, 0.f) + l1p;       // softplus(x)
            float r = 1.f / (1.f + ex);
            float p = (x >= 0.f) ? r : (1.f - r); // sigmoid(x)
            float p2 = p * p;
            float A   = sp * p2;
            float nBv = -(x * p2);
            float omp = 1.f - p;
            float post = (sp - x) * omp * omp;
            #pragma unroll
            for (int g = 0; g < GG; ++g) {
                float a = acc[j][g];
                a = fmaf(A, u[g], a);
                a = fmaf(nBv, tu[g], a);
                a = fmaf(post, e[g], a);
                acc[j][g] = a;
            }
        }
    }

    // block-reduce TN*GG sums: wave shuffle tree, then cross-wave via LDS
    __shared__ float red[4][TN * GG];
    int lane = tid & 63, wid = tid >> 6;
    #pragma unroll
    for (int j = 0; j < TN; ++j) {
        #pragma unroll
        for (int g = 0; g < GG; ++g) {
            float v = acc[j][g];
            #pragma unroll
            for (int off = 32; off; off >>= 1) v += __shfl_down(v, off, 64);
            if (lane == 0) red[wid][j * GG + g] = v;
        }
    }
    __syncthreads();
    if (tid < TN * GG) {
        float s = red[0][tid] + red[1][tid] + red[2][tid] + red[3][tid];
        S2[(size_t)bid * (TN * GG) + tid] = s;   // [bid][j*GG+g]
    }
}

// ---------------- kernel 2: combine + score + offset costs ----------------
__global__ __launch_bounds__(256) void k_final(const float* __restrict__ S2,
                                               const float* __restrict__ validws,
                                               const float* __restrict__ ps,
                                               const float* __restrict__ po,
                                               const float* __restrict__ go,
                                               float* __restrict__ out) {
    int idx = blockIdx.x * blockDim.x + threadIdx.x;
    if (idx >= BB * NN * GG) return;
    int g = idx & 7;
    int bn = idx >> 3;               // b*NN + n
    int b = bn >> 6;
    int n = bn & 63;
    int nt = n / TN;
    int j = n % TN;

    float nk = 0.f, hsum = 0.f, osum = 0.f;
    #pragma unroll
    for (int c = 0; c < CC; ++c) {
        float v = validws[((b * CC + c) << 3) + g];
        nk += v;
        // sum the HCH hw-chunk partials for this (b,c,nt)
        float s = 0.f;
        #pragma unroll
        for (int hc = 0; hc < HCH; ++hc) {
            size_t bid2 = ((size_t)(b * CC + c) * NTILES + nt) * HCH + hc;
            s += S2[bid2 * (TN * GG) + j * GG + g];
        }
        hsum += v * s;
        int poi = (bn * CC + c) * 2;
        int goi = ((b * GG + g) * CC + c) * 2;
        float s0 = 1.f / (1.f + __expf(-po[poi]));
        float s1 = 1.f / (1.f + __expf(-po[poi + 1]));
        float d0 = s0 - go[goi];
        float d1 = s1 - go[goi + 1];
        osum += v * fmaf(d0, d0, d1 * d1);
    }
    float nkp = fmaxf(nk, 1.f);

    // score cost: ALPHA * softplus(-s) * (1-sigmoid(s))^2
    float s = ps[bn];
    float ax = fabsf(s);
    float ex = __expf(-ax);
    float spn = fmaxf(-s, 0.f) + __logf(1.f + ex);   // softplus(-s)
    float r = 1.f / (1.f + ex);
    float sg = (s >= 0.f) ? r : (1.f - r);
    float om = 1.f - sg;
    float score = 0.25f * spn * om * om;

    // HMS_W=2, SCORE_W=1, OFF_W=1, off divided by num_kp and by 2
    out[idx] = 2.f * (hsum / nkp) + score + 0.5f * (osum / nkp);
}

extern "C" void kernel_launch(void* const* d_in, const int* in_sizes, int n_in,
                              void* d_out, int out_size, void* d_ws, size_t ws_size,
                              hipStream_t stream) {
    const float* ph = (const float*)d_in[0];   // pred_hms    (B,N,C,H,W)
    const float* gh = (const float*)d_in[1];   // gt_heatmaps (B,NGT,C,H,W)
    const float* ps = (const float*)d_in[2];   // pred_scores (B,N,1)
    const float* po = (const float*)d_in[3];   // pred_offsets(B,N,C,2)
    const float* go = (const float*)d_in[4];   // gt_offsets  (B,NGT,C,2)
    float* out = (float*)d_out;                // (B,N,NGT) fp32

    const int n_s2 = BB * CC * NTILES * HCH * TN * GG;  // 34816 floats
    float* S2 = (float*)d_ws;
    float* validws = S2 + n_s2;                         // B*C*G = 272 floats

    k_valid<<<BB * GG * CC, 256, 0, stream>>>(gh, validws);
    k_hms<<<BB * CC * NTILES * HCH, 256, 0, stream>>>(ph, gh, S2);
    k_final<<<(BB * NN * GG + 255) / 256, 256, 0, stream>>>(S2, validws, ps, po, go, out);
}

// Round 3
// 113.849 us; speedup vs baseline: 1.0096x; 1.0066x over previous
//
#include <hip/hip_runtime.h>

#define BB 2
#define NN 64
#define GG 8
#define CC 17
#define HWW 4096

#define TN 4                 // preds per block (register-tiled)
#define NTILES (NN / TN)     // 16
#define HCH 2                // hw chunks
#define CHUNK (HWW / HCH)    // 2048
#define CH4 (CHUNK / 4)      // 512 float4s

// ---------------- kernel 1: heatmap focal-cost partial sums + valid max ----
// Block = (b, c, nt, hc). gt-side (u = (1-t)^4, tu = t*u, e = [t==1]) computed
// ONCE per element, reused across TN preds in registers. float4 loads.
//   t != 1: term = A*u - Bv*tu   with A = softplus(x)*p^2, Bv = x*p^2
//   t == 1: u=tu=0, term = post*e with post = (softplus(x)-x)*(1-p)^2
// Blocks with nt==0 additionally reduce max_t per g over their chunk and
// write maxpart[(b*CC+c)*HCH+hc][g] (gh >= 0, so valid == max>0) — this
// replaces the former k_valid dispatch at ~zero cost (same data, in flight).
__global__ __launch_bounds__(256) void k_hms(const float* __restrict__ ph,
                                             const float* __restrict__ gh,
                                             float* __restrict__ S2,
                                             float* __restrict__ maxpart) {
    int bid = blockIdx.x;                 // ((b*CC + c)*NTILES + nt)*HCH + hc
    int hc = bid & (HCH - 1);
    int nt = (bid / HCH) % NTILES;
    int bc = bid / (HCH * NTILES);        // b*CC + c
    int b = bc / CC;
    int c = bc % CC;
    int tid = threadIdx.x;

    const int strideC4 = CC * HWW / 4;    // float4 stride between g's / n's
    const float4* gh0 = (const float4*)(gh + ((size_t)b * GG * CC + c) * HWW
                                        + (size_t)hc * CHUNK);
    const float4* ph0 = (const float4*)(ph + ((size_t)b * NN * CC
                                        + (size_t)nt * TN * CC + c) * HWW
                                        + (size_t)hc * CHUNK);

    float acc[TN][GG];
    #pragma unroll
    for (int j = 0; j < TN; ++j)
        #pragma unroll
        for (int g = 0; g < GG; ++g) acc[j][g] = 0.f;
    float mx[GG];
    #pragma unroll
    for (int g = 0; g < GG; ++g) mx[g] = 0.f;

    for (int i = tid; i < CH4; i += 256) {
        float4 tg[GG];
        #pragma unroll
        for (int g = 0; g < GG; ++g) tg[g] = gh0[(size_t)g * strideC4 + i];
        float4 xp[TN];
        #pragma unroll
        for (int j = 0; j < TN; ++j) xp[j] = ph0[(size_t)j * strideC4 + i];

        #pragma unroll
        for (int s = 0; s < 4; ++s) {
            float u[GG], tu[GG], e[GG];
            #pragma unroll
            for (int g = 0; g < GG; ++g) {
                float t = ((const float*)&tg[g])[s];
                mx[g] = fmaxf(mx[g], t);
                float om = 1.f - t;
                float om2 = om * om;
                float uu = om2 * om2;        // (1-t)^4
                u[g] = uu;
                tu[g] = t * uu;
                e[g] = (t == 1.f) ? 1.f : 0.f;
            }
            #pragma unroll
            for (int j = 0; j < TN; ++j) {
                float x = ((const float*)&xp[j])[s];
                float ax = fabsf(x);
                float ex = __expf(-ax);
                float l1p = __logf(1.f + ex);
                float sp = fmaxf(x, 0.f) + l1p;        // softplus(x)
                float r = 1.f / (1.f + ex);
                float p = (x >= 0.f) ? r : (1.f - r);  // sigmoid(x)
                float p2 = p * p;
                float A   = sp * p2;
                float nBv = -(x * p2);
                float omp = 1.f - p;
                float post = (sp - x) * omp * omp;
                #pragma unroll
                for (int g = 0; g < GG; ++g) {
                    float a = acc[j][g];
                    a = fmaf(A, u[g], a);
                    a = fmaf(nBv, tu[g], a);
                    a = fmaf(post, e[g], a);
                    acc[j][g] = a;
                }
            }
        }
    }

    // block reductions: wave shuffle tree, then cross-wave via LDS
    __shared__ float red[4][TN * GG];
    __shared__ float redm[4][GG];
    int lane = tid & 63, wid = tid >> 6;
    if (nt == 0) {
        #pragma unroll
        for (int g = 0; g < GG; ++g) {
            float v = mx[g];
            #pragma unroll
            for (int off = 32; off; off >>= 1) v = fmaxf(v, __shfl_down(v, off, 64));
            if (lane == 0) redm[wid][g] = v;
        }
    }
    #pragma unroll
    for (int j = 0; j < TN; ++j) {
        #pragma unroll
        for (int g = 0; g < GG; ++g) {
            float v = acc[j][g];
            #pragma unroll
            for (int off = 32; off; off >>= 1) v += __shfl_down(v, off, 64);
            if (lane == 0) red[wid][j * GG + g] = v;
        }
    }
    __syncthreads();
    if (tid < TN * GG) {
        float s = red[0][tid] + red[1][tid] + red[2][tid] + red[3][tid];
        S2[(size_t)bid * (TN * GG) + tid] = s;   // [bid][j*GG+g]
    }
    if (nt == 0 && tid < GG) {
        float m = fmaxf(fmaxf(redm[0][tid], redm[1][tid]),
                        fmaxf(redm[2][tid], redm[3][tid]));
        maxpart[(size_t)(bc * HCH + hc) * GG + tid] = m;
    }
}

// ---------------- kernel 2: combine + score + offset costs ----------------
__global__ __launch_bounds__(256) void k_final(const float* __restrict__ S2,
                                               const float* __restrict__ maxpart,
                                               const float* __restrict__ ps,
                                               const float* __restrict__ po,
                                               const float* __restrict__ go,
                                               float* __restrict__ out) {
    int idx = blockIdx.x * blockDim.x + threadIdx.x;
    if (idx >= BB * NN * GG) return;
    int g = idx & 7;
    int bn = idx >> 3;               // b*NN + n
    int b = bn >> 6;
    int n = bn & 63;
    int nt = n / TN;
    int j = n % TN;

    float nk = 0.f, hsum = 0.f, osum = 0.f;
    #pragma unroll
    for (int c = 0; c < CC; ++c) {
        int bc = b * CC + c;
        float m = fmaxf(maxpart[(size_t)(bc * HCH + 0) * GG + g],
                        maxpart[(size_t)(bc * HCH + 1) * GG + g]);
        float v = (m > 0.f) ? 1.f : 0.f;
        nk += v;
        float s = 0.f;
        #pragma unroll
        for (int hc = 0; hc < HCH; ++hc) {
            size_t bid2 = ((size_t)bc * NTILES + nt) * HCH + hc;
            s += S2[bid2 * (TN * GG) + j * GG + g];
        }
        hsum += v * s;
        int poi = (bn * CC + c) * 2;
        int goi = ((b * GG + g) * CC + c) * 2;
        float s0 = 1.f / (1.f + __expf(-po[poi]));
        float s1 = 1.f / (1.f + __expf(-po[poi + 1]));
        float d0 = s0 - go[goi];
        float d1 = s1 - go[goi + 1];
        osum += v * fmaf(d0, d0, d1 * d1);
    }
    float nkp = fmaxf(nk, 1.f);

    // score cost: ALPHA * softplus(-s) * (1-sigmoid(s))^2
    float s = ps[bn];
    float ax = fabsf(s);
    float ex = __expf(-ax);
    float spn = fmaxf(-s, 0.f) + __logf(1.f + ex);   // softplus(-s)
    float r = 1.f / (1.f + ex);
    float sg = (s >= 0.f) ? r : (1.f - r);
    float om = 1.f - sg;
    float score = 0.25f * spn * om * om;

    // HMS_W=2, SCORE_W=1, OFF_W=1, off divided by num_kp and by 2
    out[idx] = 2.f * (hsum / nkp) + score + 0.5f * (osum / nkp);
}

extern "C" void kernel_launch(void* const* d_in, const int* in_sizes, int n_in,
                              void* d_out, int out_size, void* d_ws, size_t ws_size,
                              hipStream_t stream) {
    const float* ph = (const float*)d_in[0];   // pred_hms    (B,N,C,H,W)
    const float* gh = (const float*)d_in[1];   // gt_heatmaps (B,NGT,C,H,W)
    const float* ps = (const float*)d_in[2];   // pred_scores (B,N,1)
    const float* po = (const float*)d_in[3];   // pred_offsets(B,N,C,2)
    const float* go = (const float*)d_in[4];   // gt_offsets  (B,NGT,C,2)
    float* out = (float*)d_out;                // (B,N,NGT) fp32

    const int n_s2 = BB * CC * NTILES * HCH * TN * GG;  // 34816 floats
    float* S2 = (float*)d_ws;
    float* maxpart = S2 + n_s2;                         // B*CC*HCH*GG = 544 floats

    k_hms<<<BB * CC * NTILES * HCH, 256, 0, stream>>>(ph, gh, S2, maxpart);
    k_final<<<(BB * NN * GG + 255) / 256, 256, 0, stream>>>(S2, maxpart, ps, po, go, out);
}